// Round 1
// baseline (701.909 us; speedup 1.0000x reference)
//
#include <hip/hip_runtime.h>

#define T_STEPS 512
#define BATCH 256
#define DIN 256
#define HID 64
#define NCOL 256   // 4*HID
#define CHUNK_MAX 128

// ws layout (floats): Wxq[256*256] | Whq[64*256] | beff[256] | Xq[Tc*BATCH*NCOL]

// Wxq[d][col] = sum_j Wg[g][d][j]    * Wq[g][j][h],  col = g*64+h
// Whq[k][col] = sum_j Wg[g][256+k][j]* Wq[g][j][h]
// beff[col]   = sum_j bg[g][j]       * Wq[g][j][h] + bq[g][h]
__global__ __launch_bounds__(256) void precompute_kernel(
    const float* __restrict__ Wg, const float* __restrict__ bg,
    const float* __restrict__ Wq, const float* __restrict__ bq,
    float* __restrict__ Wxq, float* __restrict__ Whq, float* __restrict__ beff)
{
    int idx = blockIdx.x * 256 + threadIdx.x;
    if (idx < 65536) {
        int d = idx >> 8, col = idx & 255, g = col >> 6, h = col & 63;
        const float* wg = Wg + (size_t)g * 320 * 64 + (size_t)d * 64;
        const float* wq = Wq + (size_t)g * 4096 + h;
        float s = 0.f;
        #pragma unroll 8
        for (int j = 0; j < 64; ++j) s += wg[j] * wq[(size_t)j * 64];
        Wxq[idx] = s;
    } else if (idx < 65536 + 16384) {
        int r = idx - 65536;
        int k = r >> 8, col = r & 255, g = col >> 6, h = col & 63;
        const float* wg = Wg + (size_t)g * 320 * 64 + (size_t)(256 + k) * 64;
        const float* wq = Wq + (size_t)g * 4096 + h;
        float s = 0.f;
        #pragma unroll 8
        for (int j = 0; j < 64; ++j) s += wg[j] * wq[(size_t)j * 64];
        Whq[r] = s;
    } else if (idx < 65536 + 16384 + 256) {
        int col = idx - 65536 - 16384;
        int g = col >> 6, h = col & 63;
        const float* wq = Wq + (size_t)g * 4096 + h;
        const float* bgp = bg + g * 64;
        float s = bq[g * 64 + h];
        for (int j = 0; j < 64; ++j) s += bgp[j] * wq[(size_t)j * 64];
        beff[col] = s;
    }
}

// C[M][256] = A[M][256] @ Bm[256][256] + bias[256], M = gridDim.y*64
// grid = (4, M/64); N-tile index on grid.x so the 4 N-tiles of one row-panel
// are dispatch-adjacent (A panel L2 reuse).
__global__ __launch_bounds__(256) void xproj_gemm(
    const float* __restrict__ A, const float* __restrict__ Bm,
    const float* __restrict__ bias, float* __restrict__ C)
{
    __shared__ float As[16][68];   // [k][m], padded: 16B-aligned rows, 2-way max conflicts
    __shared__ float Bs[16][64];   // [k][n]
    const int nb = blockIdx.x;     // 0..3
    const int mb = blockIdx.y;
    const int tid = threadIdx.x;
    const int tx = tid & 15, ty = tid >> 4;
    const int ar = tid >> 2, ac = (tid & 3) << 2;
    const float* Ab = A + (size_t)mb * 64 * 256;
    const float* Bb = Bm + nb * 64;
    float acc[4][4] = {{0.f,0.f,0.f,0.f},{0.f,0.f,0.f,0.f},{0.f,0.f,0.f,0.f},{0.f,0.f,0.f,0.f}};

    for (int k0 = 0; k0 < 256; k0 += 16) {
        float4 av = *reinterpret_cast<const float4*>(Ab + (size_t)ar * 256 + k0 + ac);
        int kb = tid >> 6, nn = tid & 63;
        float bv0 = Bb[(size_t)(k0 + kb + 0)  * 256 + nn];
        float bv1 = Bb[(size_t)(k0 + kb + 4)  * 256 + nn];
        float bv2 = Bb[(size_t)(k0 + kb + 8)  * 256 + nn];
        float bv3 = Bb[(size_t)(k0 + kb + 12) * 256 + nn];
        __syncthreads();
        As[ac + 0][ar] = av.x; As[ac + 1][ar] = av.y;
        As[ac + 2][ar] = av.z; As[ac + 3][ar] = av.w;
        Bs[kb + 0][nn] = bv0; Bs[kb + 4][nn] = bv1;
        Bs[kb + 8][nn] = bv2; Bs[kb + 12][nn] = bv3;
        __syncthreads();
        #pragma unroll
        for (int k = 0; k < 16; ++k) {
            float4 a = *reinterpret_cast<const float4*>(&As[k][ty << 2]);
            float4 b = *reinterpret_cast<const float4*>(&Bs[k][tx << 2]);
            acc[0][0] += a.x * b.x; acc[0][1] += a.x * b.y; acc[0][2] += a.x * b.z; acc[0][3] += a.x * b.w;
            acc[1][0] += a.y * b.x; acc[1][1] += a.y * b.y; acc[1][2] += a.y * b.z; acc[1][3] += a.y * b.w;
            acc[2][0] += a.z * b.x; acc[2][1] += a.z * b.y; acc[2][2] += a.z * b.z; acc[2][3] += a.z * b.w;
            acc[3][0] += a.w * b.x; acc[3][1] += a.w * b.y; acc[3][2] += a.w * b.z; acc[3][3] += a.w * b.w;
        }
    }
    float4 bsv = *reinterpret_cast<const float4*>(bias + nb * 64 + (tx << 2));
    #pragma unroll
    for (int i = 0; i < 4; ++i) {
        float4 o;
        o.x = acc[i][0] + bsv.x; o.y = acc[i][1] + bsv.y;
        o.z = acc[i][2] + bsv.z; o.w = acc[i][3] + bsv.w;
        *reinterpret_cast<float4*>(C + (size_t)(mb * 64 + (ty << 2) + i) * 256 + nb * 64 + (tx << 2)) = o;
    }
}

// One block per batch element. Thread tid owns gate-column tid (gate = tid>>6,
// h = tid&63): its Whq column lives in registers for the whole kernel.
// Xq chunk layout: [nsteps][BATCH][256].
__global__ __launch_bounds__(256) void lstm_seq(
    const float* __restrict__ Xq, const float* __restrict__ Whq,
    float* __restrict__ out, float* __restrict__ hx, float* __restrict__ cx,
    int nsteps, int t0, int first)
{
    __shared__ float hbuf[2][64];
    __shared__ float act_s[256];
    const int b = blockIdx.x;
    const int tid = threadIdx.x;

    float wcol[64];
    #pragma unroll
    for (int k = 0; k < 64; ++k) wcol[k] = Whq[k * 256 + tid];   // coalesced per k

    float c_reg = 0.f;
    if (tid < 64) {
        c_reg = first ? 0.f : cx[b * 64 + tid];
        hbuf[0][tid] = first ? 0.f : hx[b * 64 + tid];
    }
    __syncthreads();

    const float* xrow = Xq + (size_t)b * 256 + tid;
    const int gate = tid >> 6;          // wave-uniform
    float xq = xrow[0];

    for (int tl = 0; tl < nsteps; ++tl) {
        // prefetch next step's Xq element (hides global latency under compute)
        float xq_n = (tl + 1 < nsteps) ? xrow[(size_t)(tl + 1) * (BATCH * NCOL)] : 0.f;
        const int p = tl & 1;
        float a0 = 0.f, a1 = 0.f, a2 = 0.f, a3 = 0.f;
        #pragma unroll
        for (int k4 = 0; k4 < 16; ++k4) {
            float4 hv = *reinterpret_cast<const float4*>(&hbuf[p][k4 << 2]); // broadcast
            a0 += hv.x * wcol[k4 * 4 + 0];
            a1 += hv.y * wcol[k4 * 4 + 1];
            a2 += hv.z * wcol[k4 * 4 + 2];
            a3 += hv.w * wcol[k4 * 4 + 3];
        }
        float q = xq + ((a0 + a1) + (a2 + a3));
        float act;
        if (gate == 2) {                 // tanh gate (wave 2 only — uniform branch)
            act = 1.f - 2.f / (__expf(q + q) + 1.f);
        } else {                          // sigmoid gates
            act = 1.f / (1.f + __expf(-q));
        }
        act_s[tid] = act;
        __syncthreads();
        if (tid < 64) {
            float f  = act_s[tid];
            float ii = act_s[64 + tid];
            float gg = act_s[128 + tid];
            float oo = act_s[192 + tid];
            c_reg = f * c_reg + ii * gg;
            float hn = oo * (1.f - 2.f / (__expf(c_reg + c_reg) + 1.f));
            hbuf[p ^ 1][tid] = hn;
            out[((size_t)(t0 + tl) * BATCH + b) * HID + tid] = hn;
        }
        xq = xq_n;
        __syncthreads();
    }
    if (tid < 64) {
        cx[b * 64 + tid] = c_reg;
        hx[b * 64 + tid] = hbuf[nsteps & 1][tid];
    }
}

extern "C" void kernel_launch(void* const* d_in, const int* in_sizes, int n_in,
                              void* d_out, int out_size, void* d_ws, size_t ws_size,
                              hipStream_t stream) {
    const float* inputs = (const float*)d_in[0];
    const float* Wg = (const float*)d_in[1];
    const float* bg = (const float*)d_in[2];
    const float* Wq = (const float*)d_in[3];
    const float* bq = (const float*)d_in[4];

    float* out = (float*)d_out;                        // [T,B,64]
    float* hx = out + (size_t)T_STEPS * BATCH * HID;   // [B,64]
    float* cx = hx + BATCH * HID;                      // [B,64]

    float* Wxq = (float*)d_ws;          // 65536 floats
    float* Whq = Wxq + 65536;           // 16384 floats
    float* beff = Whq + 16384;          // 256 floats
    float* Xq = beff + 256;             // Tc*BATCH*NCOL floats

    size_t head_bytes = (size_t)(65536 + 16384 + 256) * 4;
    size_t per_step = (size_t)BATCH * NCOL * 4;  // 256 KiB per time step
    int Tc = 1;
    if (ws_size > head_bytes) {
        size_t fit = (ws_size - head_bytes) / per_step;
        if (fit < 1) fit = 1;
        if (fit > CHUNK_MAX) fit = CHUNK_MAX;
        Tc = (int)fit;
    }

    precompute_kernel<<<dim3(321), dim3(256), 0, stream>>>(Wg, bg, Wq, bq, Wxq, Whq, beff);

    int first = 1;
    for (int t0 = 0; t0 < T_STEPS; t0 += Tc) {
        int cur = (T_STEPS - t0 < Tc) ? (T_STEPS - t0) : Tc;
        xproj_gemm<<<dim3(4, cur * 4), dim3(256), 0, stream>>>(
            inputs + (size_t)t0 * BATCH * DIN, Wxq, beff, Xq);
        lstm_seq<<<dim3(256), dim3(256), 0, stream>>>(
            Xq, Whq, out, hx, cx, cur, t0, first);
        first = 0;
    }
}

// Round 2
// 635.412 us; speedup vs baseline: 1.1047x; 1.1047x over previous
//
#include <hip/hip_runtime.h>
#include <hip/hip_bf16.h>

#define T_STEPS 512
#define BATCH 256
#define DIN 256
#define HID 64
#define NCOL 256   // 4*HID
#define CHUNK_MAX 512

typedef __attribute__((ext_vector_type(8))) short short8;
typedef __attribute__((ext_vector_type(4))) float f32x4;

__device__ __forceinline__ ushort bfr(float f) {
    __hip_bfloat16 h = __float2bfloat16(f);
    ushort u; __builtin_memcpy(&u, &h, 2); return u;
}
__device__ __forceinline__ float bff(ushort u) {
    unsigned v = (unsigned)u << 16; float f; __builtin_memcpy(&f, &v, 4); return f;
}

// ws layout (bytes):
//   WbfT  : ushort[256*256]  @ 0        (WbfT[n][k] = bf16(Wxq[k][n]))
//   Whq   : float [64*256]   @ 131072   (Whq[k][col])
//   beff  : float [256]      @ 196608
//   Xq    : float            @ 197632   ([t][b][256] per chunk)

__global__ __launch_bounds__(256) void precompute_kernel(
    const float* __restrict__ Wg, const float* __restrict__ bg,
    const float* __restrict__ Wq, const float* __restrict__ bq,
    ushort* __restrict__ WbfT, float* __restrict__ Whq, float* __restrict__ beff)
{
    int idx = blockIdx.x * 256 + threadIdx.x;
    if (idx < 65536) {
        // WbfT[n][k]: n = idx>>8 (g,h), k = idx&255 (input dim d)
        int n = idx >> 8, k = idx & 255, g = n >> 6, h = n & 63;
        const float* wg = Wg + (size_t)g * 320 * 64 + (size_t)k * 64;
        const float* wq = Wq + (size_t)g * 4096 + h;
        float s = 0.f;
        #pragma unroll 8
        for (int j = 0; j < 64; ++j) s += wg[j] * wq[(size_t)j * 64];
        WbfT[idx] = bfr(s);
    } else if (idx < 65536 + 16384) {
        int r = idx - 65536;
        int k = r >> 8, col = r & 255, g = col >> 6, h = col & 63;
        const float* wg = Wg + (size_t)g * 320 * 64 + (size_t)(256 + k) * 64;
        const float* wq = Wq + (size_t)g * 4096 + h;
        float s = 0.f;
        #pragma unroll 8
        for (int j = 0; j < 64; ++j) s += wg[j] * wq[(size_t)j * 64];
        Whq[r] = s;
    } else if (idx < 65536 + 16384 + 256) {
        int col = idx - 65536 - 16384;
        int g = col >> 6, h = col & 63;
        const float* wq = Wq + (size_t)g * 4096 + h;
        const float* bgp = bg + g * 64;
        float s = bq[g * 64 + h];
        for (int j = 0; j < 64; ++j) s += bgp[j] * wq[(size_t)j * 64];
        beff[col] = s;
    }
}

// C[M][256] = (Ahi+Alo)[M][256] @ W[256][256] + beff, bf16 MFMA, 2-term split on A.
// One block = 128 M-rows x full N=256 (A fetched exactly once). B from WbfT[n][k].
__global__ __launch_bounds__(256) void xproj_mfma(
    const float* __restrict__ A, const ushort* __restrict__ BT,
    const float* __restrict__ beff, float* __restrict__ C)
{
    __shared__ ushort Ah[128 * 64];   // [row][k] bf16, 128B rows, XOR-swizzled
    __shared__ ushort Al[128 * 64];
    __shared__ ushort Bs[256 * 64];   // [n][k] bf16, 128B rows, XOR-swizzled
    const int tid = threadIdx.x;
    const int wave = tid >> 6, lane = tid & 63;
    const int mb = blockIdx.x;
    const float* Ab = A + (size_t)mb * 128 * 256;

    f32x4 acc[2][16];
    #pragma unroll
    for (int m = 0; m < 2; ++m)
        #pragma unroll
        for (int n = 0; n < 16; ++n) acc[m][n] = (f32x4){0.f, 0.f, 0.f, 0.f};

    for (int k0 = 0; k0 < 256; k0 += 64) {
        // ---- stage A (128 rows x 64 fp32 -> bf16 hi/lo) ----
        #pragma unroll
        for (int it = 0; it < 4; ++it) {
            int li = tid + it * 256;            // 0..1023
            int row = li >> 3, c2 = li & 7;     // 8 floats per (row,c2)
            const float4 f0 = *reinterpret_cast<const float4*>(Ab + (size_t)row * 256 + k0 + c2 * 8);
            const float4 f1 = *reinterpret_cast<const float4*>(Ab + (size_t)row * 256 + k0 + c2 * 8 + 4);
            float fs[8] = {f0.x, f0.y, f0.z, f0.w, f1.x, f1.y, f1.z, f1.w};
            short8 hi, lo;
            #pragma unroll
            for (int j = 0; j < 8; ++j) {
                ushort h = bfr(fs[j]);
                hi[j] = (short)h;
                lo[j] = (short)bfr(fs[j] - bff(h));
            }
            int dst = (row * 128 + c2 * 16) ^ ((row & 7) << 4);
            *reinterpret_cast<short8*>((char*)Ah + dst) = hi;
            *reinterpret_cast<short8*>((char*)Al + dst) = lo;
        }
        // ---- stage B (256 n-rows x 64 k bf16) ----
        #pragma unroll
        for (int it = 0; it < 8; ++it) {
            int li = tid + it * 256;            // 0..2047
            int row = li >> 3, c = li & 7;
            short8 v = *reinterpret_cast<const short8*>(BT + (size_t)row * 256 + k0 + c * 8);
            int dst = (row * 128 + c * 16) ^ ((row & 7) << 4);
            *reinterpret_cast<short8*>((char*)Bs + dst) = v;
        }
        __syncthreads();
        #pragma unroll
        for (int ks = 0; ks < 2; ++ks) {
            const int kk = ks * 32 + (lane >> 4) * 8;   // k within LDS tile
            short8 a_h[2], a_l[2];
            #pragma unroll
            for (int mf = 0; mf < 2; ++mf) {
                int row = wave * 32 + mf * 16 + (lane & 15);
                int off = (row * 128 + kk * 2) ^ ((row & 7) << 4);
                a_h[mf] = *reinterpret_cast<const short8*>((char*)Ah + off);
                a_l[mf] = *reinterpret_cast<const short8*>((char*)Al + off);
            }
            #pragma unroll
            for (int nf = 0; nf < 16; ++nf) {
                int col = nf * 16 + (lane & 15);
                int boff = (col * 128 + kk * 2) ^ ((col & 7) << 4);
                short8 b = *reinterpret_cast<const short8*>((char*)Bs + boff);
                #pragma unroll
                for (int mf = 0; mf < 2; ++mf) {
                    acc[mf][nf] = __builtin_amdgcn_mfma_f32_16x16x32_bf16(a_h[mf], b, acc[mf][nf], 0, 0, 0);
                    acc[mf][nf] = __builtin_amdgcn_mfma_f32_16x16x32_bf16(a_l[mf], b, acc[mf][nf], 0, 0, 0);
                }
            }
        }
        __syncthreads();
    }
    // epilogue: C/D layout col=lane&15, row=(lane>>4)*4+j (m89-verified)
    #pragma unroll
    for (int nf = 0; nf < 16; ++nf) {
        int col = nf * 16 + (lane & 15);
        float bias = beff[col];
        #pragma unroll
        for (int mf = 0; mf < 2; ++mf) {
            int r0 = mb * 128 + wave * 32 + mf * 16 + (lane >> 4) * 4;
            #pragma unroll
            for (int j = 0; j < 4; ++j)
                C[(size_t)(r0 + j) * 256 + col] = acc[mf][nf][j] + bias;
        }
    }
}

// One block per batch element, 4 waves. Thread tid owns gate-column tid
// (gate=wave=tid>>6, h=tid&63). Every wave redundantly computes the cell
// update for all 64 h, so h lives in registers (lane l of every wave holds
// h[l]) and the recurrent dot uses v_readlane broadcast — no LDS for h.
// One raw s_barrier per step (lgkmcnt-only wait: out-store and Xq prefetch
// are never drained on the critical path). act_s double-buffered.
__global__ __launch_bounds__(256) void lstm_seq(
    const float* __restrict__ Xq, const float* __restrict__ Whq,
    float* __restrict__ out, float* __restrict__ hx, float* __restrict__ cx,
    int nsteps, int t0, int first)
{
    __shared__ float act_s[2][256];
    const int b = blockIdx.x;
    const int tid = threadIdx.x;
    const int lane = tid & 63, wave = tid >> 6;

    float wcol[64];
    #pragma unroll
    for (int k = 0; k < 64; ++k) wcol[k] = Whq[k * 256 + tid];   // coalesced

    float c_reg, hn;
    if (first) { c_reg = 0.f; hn = 0.f; }
    else { c_reg = cx[b * 64 + lane]; hn = hx[b * 64 + lane]; }

    const float* xrow = Xq + (size_t)b * 256 + tid;
    float xq0 = xrow[0];
    float xq1 = (nsteps > 1) ? xrow[(size_t)BATCH * NCOL] : 0.f;

    for (int tl = 0; tl < nsteps; ++tl) {
        float xq2 = (tl + 2 < nsteps) ? xrow[(size_t)(tl + 2) * BATCH * NCOL] : 0.f;
        const int p = tl & 1;
        unsigned hu = __float_as_uint(hn);
        float a0 = 0.f, a1 = 0.f, a2 = 0.f, a3 = 0.f;
        #pragma unroll
        for (int k = 0; k < 64; k += 4) {
            a0 += __uint_as_float(__builtin_amdgcn_readlane(hu, k + 0)) * wcol[k + 0];
            a1 += __uint_as_float(__builtin_amdgcn_readlane(hu, k + 1)) * wcol[k + 1];
            a2 += __uint_as_float(__builtin_amdgcn_readlane(hu, k + 2)) * wcol[k + 2];
            a3 += __uint_as_float(__builtin_amdgcn_readlane(hu, k + 3)) * wcol[k + 3];
        }
        float q = xq0 + ((a0 + a1) + (a2 + a3));
        float act;
        if (wave == 2) act = 1.f - 2.f / (__expf(q + q) + 1.f);        // tanh
        else           act = 1.f / (1.f + __expf(-q));                  // sigmoid
        act_s[p][tid] = act;
        asm volatile("s_waitcnt lgkmcnt(0)\n\ts_barrier" ::: "memory");
        float f  = act_s[p][lane];
        float ii = act_s[p][64 + lane];
        float gg = act_s[p][128 + lane];
        float oo = act_s[p][192 + lane];
        c_reg = f * c_reg + ii * gg;
        hn = oo * (1.f - 2.f / (__expf(c_reg + c_reg) + 1.f));
        if (wave == 0) out[((size_t)(t0 + tl) * BATCH + b) * HID + lane] = hn;
        xq0 = xq1; xq1 = xq2;
    }
    if (wave == 0) {
        cx[b * 64 + lane] = c_reg;
        hx[b * 64 + lane] = hn;
    }
}

extern "C" void kernel_launch(void* const* d_in, const int* in_sizes, int n_in,
                              void* d_out, int out_size, void* d_ws, size_t ws_size,
                              hipStream_t stream) {
    const float* inputs = (const float*)d_in[0];
    const float* Wg = (const float*)d_in[1];
    const float* bg = (const float*)d_in[2];
    const float* Wq = (const float*)d_in[3];
    const float* bq = (const float*)d_in[4];

    float* out = (float*)d_out;                        // [T,B,64]
    float* hx = out + (size_t)T_STEPS * BATCH * HID;   // [B,64]
    float* cx = hx + BATCH * HID;                      // [B,64]

    char* ws = (char*)d_ws;
    ushort* WbfT = (ushort*)ws;                        // 131072 B
    float* Whq  = (float*)(ws + 131072);               // 65536 B
    float* beff = (float*)(ws + 196608);               // 1024 B
    float* Xq   = (float*)(ws + 197632);

    const size_t head_bytes = 197632;
    const size_t per_step = (size_t)BATCH * NCOL * 4;  // 256 KiB
    int Tc = 1;
    if (ws_size > head_bytes) {
        size_t fit = (ws_size - head_bytes) / per_step;
        if (fit < 1) fit = 1;
        if (fit > CHUNK_MAX) fit = CHUNK_MAX;
        Tc = (int)fit;
    }

    precompute_kernel<<<dim3(321), dim3(256), 0, stream>>>(Wg, bg, Wq, bq, WbfT, Whq, beff);

    int first = 1;
    for (int t0 = 0; t0 < T_STEPS; t0 += Tc) {
        int cur = (T_STEPS - t0 < Tc) ? (T_STEPS - t0) : Tc;
        xproj_mfma<<<dim3(cur * 2), dim3(256), 0, stream>>>(
            inputs + (size_t)t0 * BATCH * DIN, WbfT, beff, Xq);
        lstm_seq<<<dim3(256), dim3(256), 0, stream>>>(
            Xq, Whq, out, hx, cx, cur, t0, first);
        first = 0;
    }
}

// Round 5
// 524.601 us; speedup vs baseline: 1.3380x; 1.2112x over previous
//
#include <hip/hip_runtime.h>
#include <hip/hip_bf16.h>

#define T_STEPS 512
#define BATCH 256
#define DIN 256
#define HID 64
#define NCOL 256   // 4*HID
#define CHUNK_MAX 512

typedef __attribute__((ext_vector_type(8))) short short8;
typedef __attribute__((ext_vector_type(4))) float f32x4;

__device__ __forceinline__ ushort bfr(float f) {
    __hip_bfloat16 h = __float2bfloat16(f);
    ushort u; __builtin_memcpy(&u, &h, 2); return u;
}
__device__ __forceinline__ float bff(ushort u) {
    unsigned v = (unsigned)u << 16; float f; __builtin_memcpy(&f, &v, 4); return f;
}

// ws layout (bytes):
//   WbfT  : ushort[256*256]  @ 0        (WbfT[n][k] = bf16(Wxq[k][n]))
//   Whq   : float [64*256]   @ 131072   (Whq[k][col])
//   beff  : float [256]      @ 196608
//   Xq    : float            @ 197632   ([t][b][256] per chunk)

__global__ __launch_bounds__(256) void precompute_kernel(
    const float* __restrict__ Wg, const float* __restrict__ bg,
    const float* __restrict__ Wq, const float* __restrict__ bq,
    ushort* __restrict__ WbfT, float* __restrict__ Whq, float* __restrict__ beff)
{
    int idx = blockIdx.x * 256 + threadIdx.x;
    if (idx < 65536) {
        // WbfT[n][k]: n = idx>>8 (g,h), k = idx&255 (input dim d)
        int n = idx >> 8, k = idx & 255, g = n >> 6, h = n & 63;
        const float* wg = Wg + (size_t)g * 320 * 64 + (size_t)k * 64;
        const float* wq = Wq + (size_t)g * 4096 + h;
        float s = 0.f;
        #pragma unroll 8
        for (int j = 0; j < 64; ++j) s += wg[j] * wq[(size_t)j * 64];
        WbfT[idx] = bfr(s);
    } else if (idx < 65536 + 16384) {
        int r = idx - 65536;
        int k = r >> 8, col = r & 255, g = col >> 6, h = col & 63;
        const float* wg = Wg + (size_t)g * 320 * 64 + (size_t)(256 + k) * 64;
        const float* wq = Wq + (size_t)g * 4096 + h;
        float s = 0.f;
        #pragma unroll 8
        for (int j = 0; j < 64; ++j) s += wg[j] * wq[(size_t)j * 64];
        Whq[r] = s;
    } else if (idx < 65536 + 16384 + 256) {
        int col = idx - 65536 - 16384;
        int g = col >> 6, h = col & 63;
        const float* wq = Wq + (size_t)g * 4096 + h;
        const float* bgp = bg + g * 64;
        float s = bq[g * 64 + h];
        for (int j = 0; j < 64; ++j) s += bgp[j] * wq[(size_t)j * 64];
        beff[col] = s;
    }
}

// C[M][256] = (Ahi+Alo)[M][256] @ W[256][256] + beff, bf16 MFMA, 2-term split on A.
// One block = 128 M-rows x full N=256 (A fetched exactly once). B from WbfT[n][k].
__global__ __launch_bounds__(256) void xproj_mfma(
    const float* __restrict__ A, const ushort* __restrict__ BT,
    const float* __restrict__ beff, float* __restrict__ C)
{
    __shared__ ushort Ah[128 * 64];   // [row][k] bf16, 128B rows, XOR-swizzled
    __shared__ ushort Al[128 * 64];
    __shared__ ushort Bs[256 * 64];   // [n][k] bf16, 128B rows, XOR-swizzled
    const int tid = threadIdx.x;
    const int wave = tid >> 6, lane = tid & 63;
    const int mb = blockIdx.x;
    const float* Ab = A + (size_t)mb * 128 * 256;

    f32x4 acc[2][16];
    #pragma unroll
    for (int m = 0; m < 2; ++m)
        #pragma unroll
        for (int n = 0; n < 16; ++n) acc[m][n] = (f32x4){0.f, 0.f, 0.f, 0.f};

    for (int k0 = 0; k0 < 256; k0 += 64) {
        // ---- stage A (128 rows x 64 fp32 -> bf16 hi/lo) ----
        #pragma unroll
        for (int it = 0; it < 4; ++it) {
            int li = tid + it * 256;            // 0..1023
            int row = li >> 3, c2 = li & 7;     // 8 floats per (row,c2)
            const float4 f0 = *reinterpret_cast<const float4*>(Ab + (size_t)row * 256 + k0 + c2 * 8);
            const float4 f1 = *reinterpret_cast<const float4*>(Ab + (size_t)row * 256 + k0 + c2 * 8 + 4);
            float fs[8] = {f0.x, f0.y, f0.z, f0.w, f1.x, f1.y, f1.z, f1.w};
            short8 hi, lo;
            #pragma unroll
            for (int j = 0; j < 8; ++j) {
                ushort h = bfr(fs[j]);
                hi[j] = (short)h;
                lo[j] = (short)bfr(fs[j] - bff(h));
            }
            int dst = (row * 128 + c2 * 16) ^ ((row & 7) << 4);
            *reinterpret_cast<short8*>((char*)Ah + dst) = hi;
            *reinterpret_cast<short8*>((char*)Al + dst) = lo;
        }
        // ---- stage B (256 n-rows x 64 k bf16) ----
        #pragma unroll
        for (int it = 0; it < 8; ++it) {
            int li = tid + it * 256;            // 0..2047
            int row = li >> 3, c = li & 7;
            short8 v = *reinterpret_cast<const short8*>(BT + (size_t)row * 256 + k0 + c * 8);
            int dst = (row * 128 + c * 16) ^ ((row & 7) << 4);
            *reinterpret_cast<short8*>((char*)Bs + dst) = v;
        }
        __syncthreads();
        #pragma unroll
        for (int ks = 0; ks < 2; ++ks) {
            const int kk = ks * 32 + (lane >> 4) * 8;   // k within LDS tile
            short8 a_h[2], a_l[2];
            #pragma unroll
            for (int mf = 0; mf < 2; ++mf) {
                int row = wave * 32 + mf * 16 + (lane & 15);
                int off = (row * 128 + kk * 2) ^ ((row & 7) << 4);
                a_h[mf] = *reinterpret_cast<const short8*>((char*)Ah + off);
                a_l[mf] = *reinterpret_cast<const short8*>((char*)Al + off);
            }
            #pragma unroll
            for (int nf = 0; nf < 16; ++nf) {
                int col = nf * 16 + (lane & 15);
                int boff = (col * 128 + kk * 2) ^ ((col & 7) << 4);
                short8 b = *reinterpret_cast<const short8*>((char*)Bs + boff);
                #pragma unroll
                for (int mf = 0; mf < 2; ++mf) {
                    acc[mf][nf] = __builtin_amdgcn_mfma_f32_16x16x32_bf16(a_h[mf], b, acc[mf][nf], 0, 0, 0);
                    acc[mf][nf] = __builtin_amdgcn_mfma_f32_16x16x32_bf16(a_l[mf], b, acc[mf][nf], 0, 0, 0);
                }
            }
        }
        __syncthreads();
    }
    // epilogue: C/D layout col=lane&15, row=(lane>>4)*4+j (m89-verified)
    #pragma unroll
    for (int nf = 0; nf < 16; ++nf) {
        int col = nf * 16 + (lane & 15);
        float bias = beff[col];
        #pragma unroll
        for (int mf = 0; mf < 2; ++mf) {
            int r0 = mb * 128 + wave * 32 + mf * 16 + (lane >> 4) * 4;
            #pragma unroll
            for (int j = 0; j < 4; ++j)
                C[(size_t)(r0 + j) * 256 + col] = acc[mf][nf][j] + bias;
        }
    }
}

// One block per batch element, 4 waves, 256 threads = 256 gate-columns.
// Lane mapping: gate = lane>>4, h_idx = wave*16 + (lane&15)  (col = gate*64+h_idx).
// => all 4 gates of a given h_idx live in the SAME wave: f/i/g/o gather is 4
// intra-wave shuffles (no LDS, no barrier). Only h itself crosses waves:
// each wave writes its 16 h values to double-buffered h_lds; ONE raw
// lgkmcnt-only s_barrier per step (out-stores & Xq prefetch never drained).
__global__ __launch_bounds__(256) void lstm_seq(
    const float* __restrict__ Xq, const float* __restrict__ Whq,
    float* __restrict__ out, float* __restrict__ hx, float* __restrict__ cx,
    int nsteps, int t0, int first)
{
    __shared__ float h_lds[2][64];
    const int b = blockIdx.x;
    const int tid = threadIdx.x;
    const int l = tid & 63, w = tid >> 6;
    const int l15 = l & 15, g = l >> 4;
    const int hidx = w * 16 + l15;
    const int col = g * 64 + hidx;

    float wcol[64];
    #pragma unroll
    for (int k = 0; k < 64; ++k) wcol[k] = Whq[k * 256 + col];

    const float gs = (g == 2) ? 2.0f : 1.0f;   // tanh gate folded into sigmoid
    const float gofs = gs - 1.0f;

    float c_reg, hn = 0.f;
    if (first) {
        c_reg = 0.f;
        if (g == 0) h_lds[0][hidx] = 0.f;
    } else {
        c_reg = cx[b * 64 + hidx];
        if (g == 0) h_lds[0][hidx] = hx[b * 64 + hidx];
    }
    __syncthreads();

    const float* xcol = Xq + (size_t)b * NCOL + col;
    float xq0 = xcol[0];
    float xq1 = (nsteps > 1) ? xcol[(size_t)BATCH * NCOL] : 0.f;

    for (int tl = 0; tl < nsteps; ++tl) {
        float xq2 = (tl + 2 < nsteps) ? xcol[(size_t)(tl + 2) * BATCH * NCOL] : 0.f;
        const int p = tl & 1;
        float a0 = 0.f, a1 = 0.f, a2 = 0.f, a3 = 0.f;
        #pragma unroll
        for (int k4 = 0; k4 < 16; ++k4) {
            float4 hv = *reinterpret_cast<const float4*>(&h_lds[p][k4 << 2]);  // broadcast
            a0 += hv.x * wcol[4 * k4 + 0];
            a1 += hv.y * wcol[4 * k4 + 1];
            a2 += hv.z * wcol[4 * k4 + 2];
            a3 += hv.w * wcol[4 * k4 + 3];
        }
        float q = xq0 + ((a0 + a1) + (a2 + a3));
        // branchless gate activation: g==2 -> tanh(q) = 2*sigmoid(2q)-1
        float s = 1.f / (1.f + __expf(-q * gs));
        float act = s * gs - gofs;
        // gather f,i,g,o for this h_idx — all within this wave
        float fA = __shfl(act, l15 +  0, 64);
        float iA = __shfl(act, l15 + 16, 64);
        float gA = __shfl(act, l15 + 32, 64);
        float oA = __shfl(act, l15 + 48, 64);
        c_reg = fA * c_reg + iA * gA;
        hn = oA * (1.f - 2.f / (__expf(c_reg + c_reg) + 1.f));
        if (g == 0) {
            h_lds[p ^ 1][hidx] = hn;
            out[((size_t)(t0 + tl) * BATCH + b) * HID + hidx] = hn;
        }
        asm volatile("s_waitcnt lgkmcnt(0)\n\ts_barrier" ::: "memory");
        xq0 = xq1; xq1 = xq2;
    }
    if (g == 0) {
        cx[b * 64 + hidx] = c_reg;
        hx[b * 64 + hidx] = hn;
    }
}

extern "C" void kernel_launch(void* const* d_in, const int* in_sizes, int n_in,
                              void* d_out, int out_size, void* d_ws, size_t ws_size,
                              hipStream_t stream) {
    const float* inputs = (const float*)d_in[0];
    const float* Wg = (const float*)d_in[1];
    const float* bg = (const float*)d_in[2];
    const float* Wq = (const float*)d_in[3];
    const float* bq = (const float*)d_in[4];

    float* out = (float*)d_out;                        // [T,B,64]
    float* hx = out + (size_t)T_STEPS * BATCH * HID;   // [B,64]
    float* cx = hx + BATCH * HID;                      // [B,64]

    char* ws = (char*)d_ws;
    ushort* WbfT = (ushort*)ws;                        // 131072 B
    float* Whq  = (float*)(ws + 131072);               // 65536 B
    float* beff = (float*)(ws + 196608);               // 1024 B
    float* Xq   = (float*)(ws + 197632);

    const size_t head_bytes = 197632;
    const size_t per_step = (size_t)BATCH * NCOL * 4;  // 256 KiB
    int Tc = 1;
    if (ws_size > head_bytes) {
        size_t fit = (ws_size - head_bytes) / per_step;
        if (fit < 1) fit = 1;
        if (fit > CHUNK_MAX) fit = CHUNK_MAX;
        Tc = (int)fit;
    }

    precompute_kernel<<<dim3(321), dim3(256), 0, stream>>>(Wg, bg, Wq, bq, WbfT, Whq, beff);

    int first = 1;
    for (int t0 = 0; t0 < T_STEPS; t0 += Tc) {
        int cur = (T_STEPS - t0 < Tc) ? (T_STEPS - t0) : Tc;
        xproj_mfma<<<dim3(cur * 2), dim3(256), 0, stream>>>(
            inputs + (size_t)t0 * BATCH * DIN, WbfT, beff, Xq);
        lstm_seq<<<dim3(256), dim3(256), 0, stream>>>(
            Xq, Whq, out, hx, cx, cur, t0, first);
        first = 0;
    }
}